// Round 4
// baseline (1603.962 us; speedup 1.0000x reference)
//
#include <hip/hip_runtime.h>

#define CH 128   // all channel dims are 128

// ---------------------------------------------------------------------------
// K1: nbr_sum[n][c] = sum_{m: tgt[m]==n} x[src[m]][c]   (tgt is sorted)
// ---------------------------------------------------------------------------
__global__ void seg_sum_kernel(const float* __restrict__ x,
                               const int* __restrict__ src,
                               const int* __restrict__ tgt,
                               float* __restrict__ nbr,
                               int N, int M) {
  int n = blockIdx.x;
  int c = threadIdx.x;  // 128 threads
  // lower_bound(tgt, n)
  int lo = 0, hi = M;
  while (lo < hi) { int mid = (lo + hi) >> 1; if (tgt[mid] < n) lo = mid + 1; else hi = mid; }
  int start = lo;
  // lower_bound(tgt, n+1)
  int lo2 = start; hi = M;
  while (lo2 < hi) { int mid = (lo2 + hi) >> 1; if (tgt[mid] < n + 1) lo2 = mid + 1; else hi = mid; }
  int end = lo2;
  float s = 0.f;
  for (int m = start; m < end; ++m)
    s += x[(size_t)src[m] * CH + c];
  nbr[(size_t)n * CH + c] = s;
}

// ---------------------------------------------------------------------------
// K2: P = x @ W1[0:128,:]   (blockIdx.y==0)
//     Q = nbr @ W1[128:256,:] (blockIdx.y==1)
// 32 rows x 128 cols per block, 256 threads, 4x4 register tile.
// ---------------------------------------------------------------------------
__global__ __launch_bounds__(256) void pq_gemm_kernel(
    const float* __restrict__ x, const float* __restrict__ nbr,
    const float* __restrict__ W1, float* __restrict__ P, float* __restrict__ Q,
    int N) {
  const float* A = blockIdx.y ? nbr : x;
  const float* W = W1 + (size_t)blockIdx.y * CH * CH;
  float* Out = blockIdx.y ? Q : P;

  __shared__ float sA[32][CH];
  int r0 = blockIdx.x * 32;
  for (int i = threadIdx.x; i < 32 * CH; i += 256) {
    int r = i >> 7, c = i & 127;
    int gr = r0 + r;
    sA[r][c] = (gr < N) ? A[(size_t)gr * CH + c] : 0.f;
  }
  __syncthreads();

  int tc = (threadIdx.x & 31) * 4;   // 32 col groups of 4
  int tr = (threadIdx.x >> 5) * 4;   // 8 row groups of 4
  float acc[4][4] = {};
  for (int k = 0; k < CH; ++k) {
    float4 w = *(const float4*)&W[(size_t)k * CH + tc];
    float a0 = sA[tr + 0][k], a1 = sA[tr + 1][k], a2 = sA[tr + 2][k], a3 = sA[tr + 3][k];
    acc[0][0] += a0 * w.x; acc[0][1] += a0 * w.y; acc[0][2] += a0 * w.z; acc[0][3] += a0 * w.w;
    acc[1][0] += a1 * w.x; acc[1][1] += a1 * w.y; acc[1][2] += a1 * w.z; acc[1][3] += a1 * w.w;
    acc[2][0] += a2 * w.x; acc[2][1] += a2 * w.y; acc[2][2] += a2 * w.z; acc[2][3] += a2 * w.w;
    acc[3][0] += a3 * w.x; acc[3][1] += a3 * w.y; acc[3][2] += a3 * w.z; acc[3][3] += a3 * w.w;
  }
  for (int i = 0; i < 4; ++i) {
    int gr = r0 + tr + i;
    if (gr < N) {
      float4 v = make_float4(acc[i][0], acc[i][1], acc[i][2], acc[i][3]);
      *(float4*)&Out[(size_t)gr * CH + tc] = v;
    }
  }
}

// ---------------------------------------------------------------------------
// K3: batch stats of h1[m][c] = relu(P[src[m]][c] + Q[tgt[m]][c] + b1[c])
// stats[0:128] = sum, stats[128:256] = sumsq  (atomicAdd of per-block partials)
// ---------------------------------------------------------------------------
__global__ void stats_kernel(const float* __restrict__ Pm, const float* __restrict__ Qm,
                             const float* __restrict__ b1,
                             const int* __restrict__ src, const int* __restrict__ tgt,
                             float* __restrict__ stats, int M) {
  int c = threadIdx.x;  // 128
  float bias = b1[c];
  float s = 0.f, sq = 0.f;
  for (int m = blockIdx.x; m < M; m += gridDim.x) {
    float v = Pm[(size_t)src[m] * CH + c] + Qm[(size_t)tgt[m] * CH + c] + bias;
    v = v > 0.f ? v : 0.f;
    s += v;
    sq += v * v;
  }
  atomicAdd(&stats[c], s);
  atomicAdd(&stats[CH + c], sq);
}

// ---------------------------------------------------------------------------
// K4: fold BN into W2:  W2s[k][j] = a[k]*W2[k][j],  b2p[j] = b2[j] + sum_k t[k]*W2[k][j]
//     a = gamma*rsqrt(var+eps), t = beta - mean*a
// ---------------------------------------------------------------------------
__global__ void finalize_kernel(const float* __restrict__ stats,
                                const float* __restrict__ gamma, const float* __restrict__ beta,
                                const float* __restrict__ W2, const float* __restrict__ b2,
                                float* __restrict__ W2s, float* __restrict__ b2p,
                                float invM) {
  int j = threadIdx.x;  // 128
  __shared__ float sScale[CH], sShift[CH];
  float mean = stats[j] * invM;
  float var = stats[CH + j] * invM - mean * mean;
  var = var < 0.f ? 0.f : var;
  float a = gamma[j] * rsqrtf(var + 1e-5f);
  sScale[j] = a;
  sShift[j] = beta[j] - mean * a;
  __syncthreads();
  float acc = b2[j];
  for (int k = 0; k < CH; ++k) {
    float w = W2[(size_t)k * CH + j];
    W2s[(size_t)k * CH + j] = sScale[k] * w;
    acc += sShift[k] * w;
  }
  b2p[j] = acc;
}

// ---------------------------------------------------------------------------
// K5: out[m][j] = sum_k relu(P[src[m]][k]+Q[tgt[m]][k]+b1[k]) * W2s[k][j] + b2p[j]
// 64 rows x 128 cols per block, 256 threads, 8x4 register tile, A in LDS.
// ---------------------------------------------------------------------------
__global__ __launch_bounds__(256) void gemm2_kernel(
    const float* __restrict__ Pm, const float* __restrict__ Qm,
    const float* __restrict__ b1,
    const int* __restrict__ src, const int* __restrict__ tgt,
    const float* __restrict__ W2s, const float* __restrict__ b2p,
    float* __restrict__ out, int M) {
  __shared__ float sA[64][CH];
  int m0 = blockIdx.x * 64;
  for (int i = threadIdx.x; i < 64 * CH; i += 256) {
    int r = i >> 7, c = i & 127;
    int m = m0 + r;
    float v = 0.f;
    if (m < M) {
      v = Pm[(size_t)src[m] * CH + c] + Qm[(size_t)tgt[m] * CH + c] + b1[c];
      v = v > 0.f ? v : 0.f;
    }
    sA[r][c] = v;
  }
  __syncthreads();

  int tc = (threadIdx.x & 31) * 4;   // 32 col groups of 4
  int tr = (threadIdx.x >> 5) * 8;   // 8 row groups of 8
  float acc[8][4] = {};
  for (int k = 0; k < CH; ++k) {
    float4 w = *(const float4*)&W2s[(size_t)k * CH + tc];
#pragma unroll
    for (int i = 0; i < 8; ++i) {
      float a = sA[tr + i][k];
      acc[i][0] += a * w.x; acc[i][1] += a * w.y; acc[i][2] += a * w.z; acc[i][3] += a * w.w;
    }
  }
  float4 bias = *(const float4*)&b2p[tc];
#pragma unroll
  for (int i = 0; i < 8; ++i) {
    int m = m0 + tr + i;
    if (m < M) {
      float4 v = make_float4(acc[i][0] + bias.x, acc[i][1] + bias.y,
                             acc[i][2] + bias.z, acc[i][3] + bias.w);
      *(float4*)&out[(size_t)m * CH + tc] = v;
    }
  }
}

// ---------------------------------------------------------------------------
extern "C" void kernel_launch(void* const* d_in, const int* in_sizes, int n_in,
                              void* d_out, int out_size, void* d_ws, size_t ws_size,
                              hipStream_t stream) {
  const float* x     = (const float*)d_in[0];
  const float* W1    = (const float*)d_in[1];
  const float* b1    = (const float*)d_in[2];
  const float* gamma = (const float*)d_in[3];
  const float* beta  = (const float*)d_in[4];
  const float* W2    = (const float*)d_in[5];
  const float* b2    = (const float*)d_in[6];
  const int*   src   = (const int*)d_in[7];
  const int*   tgt   = (const int*)d_in[8];
  float* out = (float*)d_out;

  const int N = in_sizes[0] / CH;
  const int M = in_sizes[7];

  float* ws = (float*)d_ws;
  size_t offNbr   = 0;
  size_t offP     = offNbr + (size_t)N * CH;
  size_t offQ     = offP   + (size_t)N * CH;
  size_t offStats = offQ   + (size_t)N * CH;
  size_t offW2s   = offStats + 256;
  size_t offB2p   = offW2s + (size_t)CH * CH;

  float* nbr   = ws + offNbr;
  float* P     = ws + offP;
  float* Q     = ws + offQ;
  float* stats = ws + offStats;
  float* W2s   = ws + offW2s;
  float* b2p   = ws + offB2p;

  // K1: segment sum
  seg_sum_kernel<<<N, CH, 0, stream>>>(x, src, tgt, nbr, N, M);

  // K2: P and Q
  dim3 g2((N + 31) / 32, 2);
  pq_gemm_kernel<<<g2, 256, 0, stream>>>(x, nbr, W1, P, Q, N);

  // zero stats, then accumulate
  hipMemsetAsync(stats, 0, 256 * sizeof(float), stream);
  stats_kernel<<<1024, CH, 0, stream>>>(P, Q, b1, src, tgt, stats, M);

  // K4: fold BN
  finalize_kernel<<<1, CH, 0, stream>>>(stats, gamma, beta, W2, b2, W2s, b2p, 1.f / (float)M);

  // K5: final GEMM
  gemm2_kernel<<<(M + 63) / 64, 256, 0, stream>>>(P, Q, b1, src, tgt, W2s, b2p, out, M);
}

// Round 5
// 968.689 us; speedup vs baseline: 1.6558x; 1.6558x over previous
//
#include <hip/hip_runtime.h>

#define CH 128   // all channel dims are 128

using bf16x8 = __attribute__((ext_vector_type(8))) short;
using f32x4  = __attribute__((ext_vector_type(4))) float;

__device__ inline unsigned short f2bf(float f) {
  union { float f; unsigned u; } v; v.f = f;
  unsigned r = (v.u + 0x7FFFu + ((v.u >> 16) & 1u)) >> 16;  // RNE
  return (unsigned short)r;
}

// ---------------------------------------------------------------------------
// K1: nbr_sum[n][c] = sum_{m: tgt[m]==n} x[src[m]][c]   (tgt is sorted)
// ---------------------------------------------------------------------------
__global__ void seg_sum_kernel(const float* __restrict__ x,
                               const int* __restrict__ src,
                               const int* __restrict__ tgt,
                               float* __restrict__ nbr,
                               int N, int M) {
  int n = blockIdx.x;
  int c = threadIdx.x;  // 128 threads
  int lo = 0, hi = M;
  while (lo < hi) { int mid = (lo + hi) >> 1; if (tgt[mid] < n) lo = mid + 1; else hi = mid; }
  int start = lo;
  int lo2 = start; hi = M;
  while (lo2 < hi) { int mid = (lo2 + hi) >> 1; if (tgt[mid] < n + 1) lo2 = mid + 1; else hi = mid; }
  int end = lo2;
  float s = 0.f;
  for (int m = start; m < end; ++m)
    s += x[(size_t)src[m] * CH + c];
  nbr[(size_t)n * CH + c] = s;
}

// ---------------------------------------------------------------------------
// K2: P = x @ W1[0:128,:]  (blockIdx.y==0),  Q = nbr @ W1[128:256,:] (==1)
// ---------------------------------------------------------------------------
__global__ __launch_bounds__(256) void pq_gemm_kernel(
    const float* __restrict__ x, const float* __restrict__ nbr,
    const float* __restrict__ W1, float* __restrict__ P, float* __restrict__ Q,
    int N) {
  const float* A = blockIdx.y ? nbr : x;
  const float* W = W1 + (size_t)blockIdx.y * CH * CH;
  float* Out = blockIdx.y ? Q : P;

  __shared__ float sA[32][CH];
  int r0 = blockIdx.x * 32;
  for (int i = threadIdx.x; i < 32 * CH; i += 256) {
    int r = i >> 7, c = i & 127;
    int gr = r0 + r;
    sA[r][c] = (gr < N) ? A[(size_t)gr * CH + c] : 0.f;
  }
  __syncthreads();

  int tc = (threadIdx.x & 31) * 4;
  int tr = (threadIdx.x >> 5) * 4;
  float acc[4][4] = {};
  for (int k = 0; k < CH; ++k) {
    float4 w = *(const float4*)&W[(size_t)k * CH + tc];
    float a0 = sA[tr + 0][k], a1 = sA[tr + 1][k], a2 = sA[tr + 2][k], a3 = sA[tr + 3][k];
    acc[0][0] += a0 * w.x; acc[0][1] += a0 * w.y; acc[0][2] += a0 * w.z; acc[0][3] += a0 * w.w;
    acc[1][0] += a1 * w.x; acc[1][1] += a1 * w.y; acc[1][2] += a1 * w.z; acc[1][3] += a1 * w.w;
    acc[2][0] += a2 * w.x; acc[2][1] += a2 * w.y; acc[2][2] += a2 * w.z; acc[2][3] += a2 * w.w;
    acc[3][0] += a3 * w.x; acc[3][1] += a3 * w.y; acc[3][2] += a3 * w.z; acc[3][3] += a3 * w.w;
  }
  for (int i = 0; i < 4; ++i) {
    int gr = r0 + tr + i;
    if (gr < N) {
      float4 v = make_float4(acc[i][0], acc[i][1], acc[i][2], acc[i][3]);
      *(float4*)&Out[(size_t)gr * CH + tc] = v;
    }
  }
}

// ---------------------------------------------------------------------------
// K3: batch stats of h1[m][c] = relu(P[src[m]][c] + Q[tgt[m]][c] + b1[c])
// 256 threads: 8 pairs per block-iteration, float4 per lane, LDS reduce,
// one atomicAdd per channel per block. stats[0:128]=sum, [128:256]=sumsq.
// ---------------------------------------------------------------------------
__global__ __launch_bounds__(256) void stats_kernel(
    const float* __restrict__ Pm, const float* __restrict__ Qm,
    const float* __restrict__ b1,
    const int* __restrict__ src, const int* __restrict__ tgt,
    float* __restrict__ stats, int M) {
  int t = threadIdx.x;
  int sub = t >> 5;          // 0..7 : which pair within the iteration
  int lane = t & 31;         // channel group (4 channels)
  float4 bias = *(const float4*)&b1[lane * 4];
  float4 s  = make_float4(0.f, 0.f, 0.f, 0.f);
  float4 sq = make_float4(0.f, 0.f, 0.f, 0.f);

  int stride = gridDim.x * 8;
  for (int m = blockIdx.x * 8 + sub; m < M; m += stride) {
    int is = src[m], it = tgt[m];
    float4 p = *(const float4*)&Pm[(size_t)is * CH + lane * 4];
    float4 q = *(const float4*)&Qm[(size_t)it * CH + lane * 4];
    float4 v;
    v.x = fmaxf(p.x + q.x + bias.x, 0.f);
    v.y = fmaxf(p.y + q.y + bias.y, 0.f);
    v.z = fmaxf(p.z + q.z + bias.z, 0.f);
    v.w = fmaxf(p.w + q.w + bias.w, 0.f);
    s.x += v.x; s.y += v.y; s.z += v.z; s.w += v.w;
    sq.x += v.x * v.x; sq.y += v.y * v.y; sq.z += v.z * v.z; sq.w += v.w * v.w;
  }

  __shared__ float red[2][8][CH];   // 8 KB
  *(float4*)&red[0][sub][lane * 4] = s;
  *(float4*)&red[1][sub][lane * 4] = sq;
  __syncthreads();
  if (t < CH) {
    float a = 0.f, b = 0.f;
#pragma unroll
    for (int s8 = 0; s8 < 8; ++s8) { a += red[0][s8][t]; b += red[1][s8][t]; }
    atomicAdd(&stats[t], a);
    atomicAdd(&stats[CH + t], b);
  }
}

// ---------------------------------------------------------------------------
// K4: fold BN into W2. Writes W2sT (bf16, TRANSPOSED: [j][k] = a[k]*W2[k][j])
// and b2p[j] = b2[j] + sum_k (beta[k]-mean[k]*a[k]) * W2[k][j]
// ---------------------------------------------------------------------------
__global__ void finalize_kernel(const float* __restrict__ stats,
                                const float* __restrict__ gamma, const float* __restrict__ beta,
                                const float* __restrict__ W2, const float* __restrict__ b2,
                                unsigned short* __restrict__ W2sT, float* __restrict__ b2p,
                                float invM) {
  int j = threadIdx.x;  // 128
  __shared__ float sScale[CH], sShift[CH];
  float mean = stats[j] * invM;
  float var = stats[CH + j] * invM - mean * mean;
  var = var < 0.f ? 0.f : var;
  float a = gamma[j] * rsqrtf(var + 1e-5f);
  sScale[j] = a;
  sShift[j] = beta[j] - mean * a;
  __syncthreads();
  float acc = b2[j];
  for (int k = 0; k < CH; ++k) {
    float w = W2[(size_t)k * CH + j];
    W2sT[(size_t)j * CH + k] = f2bf(sScale[k] * w);
    acc += sShift[k] * w;
  }
  b2p[j] = acc;
}

// ---------------------------------------------------------------------------
// K5: out[m][j] = sum_k relu(P[src[m]][k]+Q[tgt[m]][k]+b1[k]) * W2s[k][j] + b2p[j]
// bf16 MFMA 16x16x32. Block = 256 threads (4 waves), tile 128 rows x 128 cols.
// h1 tile + W2sT staged in XOR-swizzled LDS (byte ^= (row&7)<<4) so the
// stride-256B fragment reads are bank-conflict-free (G4).
// A-frag: row = l&15, k = 8*(l>>4)+e (contiguous bf16x8).
// B-frag (from W2sT, N-major): col = l&15, same k pattern.
// C/D:    col = l&15, row = 4*(l>>4)+reg   [m89-verified].
// ---------------------------------------------------------------------------
__global__ __launch_bounds__(256) void gemm2_mfma_kernel(
    const float* __restrict__ Pm, const float* __restrict__ Qm,
    const float* __restrict__ b1,
    const int* __restrict__ src, const int* __restrict__ tgt,
    const unsigned short* __restrict__ W2sT, const float* __restrict__ b2p,
    float* __restrict__ out, int M) {
  __shared__ unsigned short sA[128 * CH];  // 32 KB, swizzled
  __shared__ unsigned short sB[128 * CH];  // 32 KB, swizzled

  int t = threadIdx.x;
  int m0 = blockIdx.x * 128;

  // ---- stage B: whole W2sT (32 KB), 8 x 16B per thread, swizzled write
  {
    const uint4* g = (const uint4*)W2sT;  // 2048 16B units
#pragma unroll
    for (int i = 0; i < 8; ++i) {
      int u = t + i * 256;          // 16B-unit index
      uint4 d = g[u];
      int byte = u * 16;
      int row = byte >> 8;          // W2sT row j
      int sw = byte ^ ((row & 7) << 4);
      *(uint4*)((char*)sB + sw) = d;
    }
  }

  // ---- stage A: gather h1 rows m0..m0+127, relu, cvt bf16, swizzled write
  {
    int sub = t >> 5, lane = t & 31;
    float4 bias = *(const float4*)&b1[lane * 4];
#pragma unroll
    for (int pass = 0; pass < 16; ++pass) {
      int r = pass * 8 + sub;
      int m = m0 + r;
      float4 v = make_float4(0.f, 0.f, 0.f, 0.f);
      if (m < M) {
        int is = src[m], it = tgt[m];
        float4 p = *(const float4*)&Pm[(size_t)is * CH + lane * 4];
        float4 q = *(const float4*)&Qm[(size_t)it * CH + lane * 4];
        v.x = fmaxf(p.x + q.x + bias.x, 0.f);
        v.y = fmaxf(p.y + q.y + bias.y, 0.f);
        v.z = fmaxf(p.z + q.z + bias.z, 0.f);
        v.w = fmaxf(p.w + q.w + bias.w, 0.f);
      }
      ushort4 h;
      h.x = f2bf(v.x); h.y = f2bf(v.y); h.z = f2bf(v.z); h.w = f2bf(v.w);
      int byte = r * 256 + lane * 8;
      int sw = byte ^ ((r & 7) << 4);
      *(ushort4*)((char*)sA + sw) = h;
    }
  }
  __syncthreads();

  // ---- compute: wave w owns rows [w*32, w*32+32), all 128 cols
  int w = t >> 6, l = t & 63;
  int rlo = l & 15, khi = l >> 4;   // khi = 0..3

  f32x4 acc[2][8];
#pragma unroll
  for (int rb = 0; rb < 2; ++rb)
#pragma unroll
    for (int cb = 0; cb < 8; ++cb)
      acc[rb][cb] = (f32x4){0.f, 0.f, 0.f, 0.f};

#pragma unroll
  for (int ks = 0; ks < 4; ++ks) {
    bf16x8 a[2], b[8];
#pragma unroll
    for (int rb = 0; rb < 2; ++rb) {
      int row = w * 32 + rb * 16 + rlo;
      int byte = row * 256 + ks * 64 + khi * 16;
      a[rb] = *(bf16x8*)((char*)sA + (byte ^ ((row & 7) << 4)));
    }
#pragma unroll
    for (int cb = 0; cb < 8; ++cb) {
      int col = cb * 16 + rlo;
      int byte = col * 256 + ks * 64 + khi * 16;
      b[cb] = *(bf16x8*)((char*)sB + (byte ^ ((col & 7) << 4)));
    }
#pragma unroll
    for (int rb = 0; rb < 2; ++rb)
#pragma unroll
      for (int cb = 0; cb < 8; ++cb)
        acc[rb][cb] = __builtin_amdgcn_mfma_f32_16x16x32_bf16(a[rb], b[cb], acc[rb][cb], 0, 0, 0);
  }

  // ---- epilogue: D col = l&15, row = 4*(l>>4)+reg
#pragma unroll
  for (int rb = 0; rb < 2; ++rb) {
    int rbase = m0 + w * 32 + rb * 16 + khi * 4;
#pragma unroll
    for (int cb = 0; cb < 8; ++cb) {
      float bias = b2p[cb * 16 + rlo];
#pragma unroll
      for (int r_ = 0; r_ < 4; ++r_) {
        int m = rbase + r_;
        if (m < M)
          out[(size_t)m * CH + cb * 16 + rlo] = acc[rb][cb][r_] + bias;
      }
    }
  }
}

// ---------------------------------------------------------------------------
extern "C" void kernel_launch(void* const* d_in, const int* in_sizes, int n_in,
                              void* d_out, int out_size, void* d_ws, size_t ws_size,
                              hipStream_t stream) {
  const float* x     = (const float*)d_in[0];
  const float* W1    = (const float*)d_in[1];
  const float* b1    = (const float*)d_in[2];
  const float* gamma = (const float*)d_in[3];
  const float* beta  = (const float*)d_in[4];
  const float* W2    = (const float*)d_in[5];
  const float* b2    = (const float*)d_in[6];
  const int*   src   = (const int*)d_in[7];
  const int*   tgt   = (const int*)d_in[8];
  float* out = (float*)d_out;

  const int N = in_sizes[0] / CH;
  const int M = in_sizes[7];

  float* ws = (float*)d_ws;
  size_t offNbr   = 0;
  size_t offP     = offNbr + (size_t)N * CH;
  size_t offQ     = offP   + (size_t)N * CH;
  size_t offStats = offQ   + (size_t)N * CH;
  size_t offB2p   = offStats + 256;
  size_t offW2sT  = offB2p + CH;          // 128*128 bf16 = 8192 floats

  float* nbr   = ws + offNbr;
  float* P     = ws + offP;
  float* Q     = ws + offQ;
  float* stats = ws + offStats;
  float* b2p   = ws + offB2p;
  unsigned short* W2sT = (unsigned short*)(ws + offW2sT);

  // K1: segment sum
  seg_sum_kernel<<<N, CH, 0, stream>>>(x, src, tgt, nbr, N, M);

  // K2: P and Q
  dim3 g2((N + 31) / 32, 2);
  pq_gemm_kernel<<<g2, 256, 0, stream>>>(x, nbr, W1, P, Q, N);

  // K3: stats (zero first)
  hipMemsetAsync(stats, 0, 256 * sizeof(float), stream);
  stats_kernel<<<2048, 256, 0, stream>>>(P, Q, b1, src, tgt, stats, M);

  // K4: fold BN -> W2sT (bf16) + b2p
  finalize_kernel<<<1, CH, 0, stream>>>(stats, gamma, beta, W2, b2, W2sT, b2p, 1.f / (float)M);

  // K5: final GEMM (bf16 MFMA)
  gemm2_mfma_kernel<<<(M + 127) / 128, 256, 0, stream>>>(P, Q, b1, src, tgt, W2sT, b2p, out, M);
}